// Round 5
// baseline (239.878 us; speedup 1.0000x reference)
//
#include <hip/hip_runtime.h>
#include <math.h>

// Converse2D on gfx950 — spectral restructuring (R4):
//   out(2y+u, 2x+v) plane = ifft136( A_uv[g] * Xhat[g] ), per (n,c,u,v)
// R4: (1) prep rewritten in fp32 (error-amplification-safe; see analysis) and
//     dispatch-fused with fwd (independent work, block-level branch);
//     (2) inv merges the v-parity pair per WG: v0 results stashed in 16 VGPRs,
//     final stores are coalesced float4 (kills the 4.3x write amplification).

#define MDIM 136
#define RS   70             // padded LDS row stride (69 stored cols + 1)
#define HC   69             // stored Hermitian half columns (0..68)
#define PLANE_HALF (MDIM*HC)   // 9384 complex per plane
#define NPLANES 256         // N*C
#define PREP_BLOCKS 64
#define LDS_FLOATS (2*MDIM*RS + 2*MDIM)   // re+im planes + cos/sin LUT
#define PI_D 3.14159265358979323846

__device__ __forceinline__ int slot136(int k) { return 17*(k & 7) + (k >> 3); }
__device__ __forceinline__ int slot68(int k)  { return 17*(k & 3) + (k >> 2); }

// ---------- symmetric 17-point DFT, in-place on strided LDS segment ----------
template<int DIR>
__device__ __forceinline__ void dft17(float* __restrict__ re, float* __restrict__ im,
                                      int base, int stride)
{
    constexpr float C17[9] = {1.f, 0.93247223f, 0.73900892f, 0.44573836f,
                              0.09226836f, -0.27366299f, -0.60263464f,
                              -0.85021714f, -0.98297310f};
    constexpr float S17[9] = {0.f, 0.36124167f, 0.67369564f, 0.89516329f,
                              0.99573418f, 0.96182564f, 0.79801723f,
                              0.52643216f, 0.18374952f};
    constexpr float d = (DIR > 0) ? 1.f : -1.f;
    float xr[17], xi[17];
#pragma unroll
    for (int n = 0; n < 17; n++) { xr[n] = re[base + n*stride]; xi[n] = im[base + n*stride]; }
    float ar[8], ai[8], br[8], bi[8];
#pragma unroll
    for (int n = 1; n <= 8; n++) {
        ar[n-1] = xr[n] + xr[17-n];  ai[n-1] = xi[n] + xi[17-n];
        br[n-1] = xr[n] - xr[17-n];  bi[n-1] = xi[n] - xi[17-n];
    }
    float s0r = xr[0], s0i = xi[0];
#pragma unroll
    for (int n = 0; n < 8; n++) { s0r += ar[n]; s0i += ai[n]; }
    re[base] = s0r; im[base] = s0i;
#pragma unroll
    for (int k = 1; k <= 8; k++) {
        float Pr = xr[0], Pi = xi[0], Qr = 0.f, Qi = 0.f;
#pragma unroll
        for (int n = 1; n <= 8; n++) {
            int m = (k*n) % 17;
            float cc = (m <= 8) ? C17[m] : C17[17-m];
            float ss = (m <= 8) ? S17[m] : -S17[17-m];
            Pr = fmaf(ar[n-1], cc, Pr);
            Pi = fmaf(ai[n-1], cc, Pi);
            Qr = fmaf(br[n-1], ss, Qr);
            Qi = fmaf(bi[n-1], ss, Qi);
        }
        re[base + k*stride]        = Pr - d*Qi;
        im[base + k*stride]        = Pi + d*Qr;
        re[base + (17-k)*stride]   = Pr + d*Qi;
        im[base + (17-k)*stride]   = Pi - d*Qr;
    }
}

// ---------- 136-point CT (8x17) along COLUMNS ----------
template<int DIR>
__device__ void fft136_cols(float* __restrict__ re, float* __restrict__ im,
                            const float* __restrict__ lutc, const float* __restrict__ luts,
                            int ncols, int tid, int nth)
{
    constexpr float d = (DIR > 0) ? 1.0f : -1.0f;
    constexpr float C707 = 0.70710678118654752f;
    for (int e = tid; e < ncols*17; e += nth) {
        int c  = e / 17;
        int n2 = e - c*17;
        float xr[8], xi[8];
#pragma unroll
        for (int n1 = 0; n1 < 8; n1++) {
            int a = (17*n1 + n2)*RS + c;
            xr[n1] = re[a]; xi[n1] = im[a];
        }
        float e0r = xr[0]+xr[4], e0i = xi[0]+xi[4];
        float e1r = xr[0]-xr[4], e1i = xi[0]-xi[4];
        float o0r = xr[2]+xr[6], o0i = xi[2]+xi[6];
        float o1r = xr[2]-xr[6], o1i = xi[2]-xi[6];
        float E0r = e0r+o0r, E0i = e0i+o0i;
        float E2r = e0r-o0r, E2i = e0i-o0i;
        float E1r = e1r - d*o1i, E1i = e1i + d*o1r;
        float E3r = e1r + d*o1i, E3i = e1i - d*o1r;
        float f0r = xr[1]+xr[5], f0i = xi[1]+xi[5];
        float f1r = xr[1]-xr[5], f1i = xi[1]-xi[5];
        float h0r = xr[3]+xr[7], h0i = xi[3]+xi[7];
        float h1r = xr[3]-xr[7], h1i = xi[3]-xi[7];
        float O0r = f0r+h0r, O0i = f0i+h0i;
        float O2r = f0r-h0r, O2i = f0i-h0i;
        float O1r = f1r - d*h1i, O1i = f1i + d*h1r;
        float O3r = f1r + d*h1i, O3i = f1i - d*h1r;
        float t1r =  C707*(O1r - d*O1i), t1i = C707*(O1i + d*O1r);
        float t2r = -d*O2i,              t2i = d*O2r;
        float t3r = -C707*(O3r + d*O3i), t3i = C707*(d*O3r - O3i);
        float Xr[8], Xi[8];
        Xr[0]=E0r+O0r; Xi[0]=E0i+O0i;  Xr[4]=E0r-O0r; Xi[4]=E0i-O0i;
        Xr[1]=E1r+t1r; Xi[1]=E1i+t1i;  Xr[5]=E1r-t1r; Xi[5]=E1i-t1i;
        Xr[2]=E2r+t2r; Xi[2]=E2i+t2i;  Xr[6]=E2r-t2r; Xi[6]=E2i-t2i;
        Xr[3]=E3r+t3r; Xi[3]=E3i+t3i;  Xr[7]=E3r-t3r; Xi[7]=E3i-t3i;
        float wr = lutc[n2], wi = luts[n2];
        float cr = 1.f, ci = 0.f;
#pragma unroll
        for (int k1 = 0; k1 < 8; k1++) {
            int a = (17*k1 + n2)*RS + c;
            re[a] = Xr[k1]*cr - Xi[k1]*ci;
            im[a] = Xr[k1]*ci + Xi[k1]*cr;
            float ncr = cr*wr - ci*wi;
            ci = cr*wi + ci*wr; cr = ncr;
        }
    }
    __syncthreads();
    for (int e = tid; e < ncols*8; e += nth) {
        int c  = e >> 3;
        int k1 = e & 7;
        dft17<DIR>(re, im, 17*k1*RS + c, RS);
    }
    __syncthreads();
}

// ---------- 68-point CT (4x17) along ROWS ----------
template<int DIR>
__device__ void ct68_rows(float* __restrict__ re, float* __restrict__ im,
                          const float* __restrict__ lutc, const float* __restrict__ luts,
                          int tid, int nth)
{
    constexpr float d = (DIR > 0) ? 1.0f : -1.0f;
    for (int e = tid; e < MDIM*17; e += nth) {
        int row = e / 17;
        int n2  = e - row*17;
        int base = row*RS;
        float xr[4], xi[4];
#pragma unroll
        for (int n1 = 0; n1 < 4; n1++) {
            xr[n1] = re[base + 17*n1 + n2];
            xi[n1] = im[base + 17*n1 + n2];
        }
        float t0r = xr[0]+xr[2], t0i = xi[0]+xi[2];
        float t1r = xr[0]-xr[2], t1i = xi[0]-xi[2];
        float t2r = xr[1]+xr[3], t2i = xi[1]+xi[3];
        float t3r = xr[1]-xr[3], t3i = xi[1]-xi[3];
        float Xr[4], Xi[4];
        Xr[0] = t0r+t2r;      Xi[0] = t0i+t2i;
        Xr[2] = t0r-t2r;      Xi[2] = t0i-t2i;
        Xr[1] = t1r - d*t3i;  Xi[1] = t1i + d*t3r;
        Xr[3] = t1r + d*t3i;  Xi[3] = t1i - d*t3r;
        float wr = lutc[2*n2], wi = luts[2*n2];
        float cr = 1.f, ci = 0.f;
#pragma unroll
        for (int k1 = 0; k1 < 4; k1++) {
            int a = base + 17*k1 + n2;
            re[a] = Xr[k1]*cr - Xi[k1]*ci;
            im[a] = Xr[k1]*ci + Xi[k1]*cr;
            float ncr = cr*wr - ci*wi;
            ci = cr*wi + ci*wr; cr = ncr;
        }
    }
    __syncthreads();
    for (int e = tid; e < MDIM*4; e += nth) {
        int row = e >> 2;
        int k1  = e & 3;
        dft17<DIR>(re, im, row*RS + 17*k1, 1);
    }
    __syncthreads();
}

// ---------- Fused prep(fp32) + forward kernel ----------
// blocks 0..63: prep (one channel each); blocks 64..319: fwd (one plane each).
__global__ __launch_bounds__(1024, 8) void fwdprep_kernel(const float* __restrict__ x,
                                                          const float* __restrict__ weight,
                                                          const float* __restrict__ bias,
                                                          float2* __restrict__ Xhat,
                                                          float2* __restrict__ Abuf)
{
    extern __shared__ float smem[];
    const int tid = threadIdx.x, nth = blockDim.x;

    if (blockIdx.x < PREP_BLOCKS) {
        // ===== prep path (fp32; LDS: tabc[272], tabs[272], w[25]) =====
        float* tabc = smem;
        float* tabs = smem + 272;
        float* wsh  = smem + 544;
        const int c = blockIdx.x;
        for (int t = tid; t < 272; t += nth) {
            float s, co; sincosf((float)(-2.0*PI_D/272.0)*(float)t, &s, &co);
            tabc[t] = co; tabs[t] = s;
        }
        if (tid < 25) wsh[tid] = weight[c*25 + tid];
        __syncthreads();
        const float r = 1.f/(1.f + expf(9.f - bias[c])) + 1e-5f;
        const float scale = 1.f/73984.f;

        for (int e = tid; e < PLANE_HALF; e += nth) {
            int g1 = e / HC, g2 = e - g1*HC;
            float c1 = tabc[g1], s1 = tabs[g1];
            float c2 = tabc[g2], s2 = tabs[g2];
            float e1r[5], e1i[5], e2r[5], e2i[5];
            e1r[2]=1.f; e1i[2]=0.f; e1r[3]=c1; e1i[3]=s1;
            e1r[4]=c1*c1-s1*s1; e1i[4]=2.f*c1*s1;
            e1r[1]=c1; e1i[1]=-s1; e1r[0]=e1r[4]; e1i[0]=-e1i[4];
            e2r[2]=1.f; e2i[2]=0.f; e2r[3]=c2; e2i[3]=s2;
            e2r[4]=c2*c2-s2*s2; e2i[4]=2.f*c2*s2;
            e2r[1]=c2; e2i[1]=-s2; e2r[0]=e2r[4]; e2i[0]=-e2i[4];

            float Fr[2][2] = {{0,0},{0,0}}, Fi[2][2] = {{0,0},{0,0}};
#pragma unroll
            for (int a = 0; a < 5; a++) {
                float r0r=0,r0i=0,r1r=0,r1i=0;
#pragma unroll
                for (int b = 0; b < 5; b++) {
                    float wv = wsh[a*5+b];
                    float pr = wv*e2r[b], pi = wv*e2i[b];
                    r0r += pr; r0i += pi;
                    if (b & 1) { r1r -= pr; r1i -= pi; } else { r1r += pr; r1i += pi; }
                }
                float Er = e1r[a], Ei = e1i[a];
                float t0r = Er*r0r - Ei*r0i, t0i = Er*r0i + Ei*r0r;
                float t1r = Er*r1r - Ei*r1i, t1i = Er*r1i + Ei*r1r;
                Fr[0][0] += t0r; Fi[0][0] += t0i; Fr[0][1] += t1r; Fi[0][1] += t1i;
                if (a & 1) { Fr[1][0] -= t0r; Fi[1][0] -= t0i; Fr[1][1] -= t1r; Fi[1][1] -= t1i; }
                else       { Fr[1][0] += t0r; Fi[1][0] += t0i; Fr[1][1] += t1r; Fi[1][1] += t1i; }
            }
            float ur[2] = {1.f+c1, 1.f-c1}, ui[2] = {s1, -s1};
            float vr[2] = {1.f+c2, 1.f-c2}, vi[2] = {s2, -s2};
            float Br[2][2], Bi[2][2];
            float invW = 0.f, Qr = 0.f, Qi = 0.f;
#pragma unroll
            for (int a1 = 0; a1 < 2; a1++)
#pragma unroll
                for (int b1 = 0; b1 < 2; b1++) {
                    Br[a1][b1] = ur[a1]*vr[b1] - ui[a1]*vi[b1];
                    Bi[a1][b1] = ur[a1]*vi[b1] + ui[a1]*vr[b1];
                    invW += Fr[a1][b1]*Fr[a1][b1] + Fi[a1][b1]*Fi[a1][b1];
                    Qr += Fr[a1][b1]*Br[a1][b1] - Fi[a1][b1]*Bi[a1][b1];
                    Qi += Fr[a1][b1]*Bi[a1][b1] + Fi[a1][b1]*Br[a1][b1];
                }
            invW *= 0.25f; Qr *= 0.25f; Qi *= 0.25f;
            float den = 1.f/(invW + r);
            float Sr = (1.f - Qr)*den, Si = -Qi*den;
            float Mr[2][2], Mi[2][2];
#pragma unroll
            for (int a1 = 0; a1 < 2; a1++)
#pragma unroll
                for (int b1 = 0; b1 < 2; b1++) {
                    Mr[a1][b1] = Br[a1][b1] + Fr[a1][b1]*Sr + Fi[a1][b1]*Si;
                    Mi[a1][b1] = Bi[a1][b1] + Fr[a1][b1]*Si - Fi[a1][b1]*Sr;
                }
#pragma unroll
            for (int uu = 0; uu < 2; uu++)
#pragma unroll
                for (int vv = 0; vv < 2; vv++) {
                    float sr=0.f, si=0.f;
#pragma unroll
                    for (int a1 = 0; a1 < 2; a1++)
#pragma unroll
                        for (int b1 = 0; b1 < 2; b1++) {
                            if ((a1*uu + b1*vv) & 1) { sr -= Mr[a1][b1]; si -= Mi[a1][b1]; }
                            else                     { sr += Mr[a1][b1]; si += Mi[a1][b1]; }
                        }
                    int t = g1*uu + g2*vv;              // <= 203 < 272
                    float pc = tabc[t], ps = -tabs[t];  // exp(+i*pi*t/136)
                    float2 outv;
                    outv.x = (pc*sr - ps*si)*scale;
                    outv.y = (pc*si + ps*sr)*scale;
                    Abuf[((size_t)(c*4 + uu*2 + vv))*PLANE_HALF + e] = outv;
                }
        }
        return;
    }

    // ===== fwd path: r2c half-spectrum, one plane per block =====
    float* re   = smem;
    float* im   = smem + MDIM*RS;
    float* lutc = smem + 2*MDIM*RS;
    float* luts = lutc + MDIM;
    const int plane = blockIdx.x - PREP_BLOCKS;

    for (int t = tid; t < MDIM; t += nth) {
        double s, c; sincos(-2.0*PI_D*(double)t/136.0, &s, &c);
        lutc[t] = (float)c; luts[t] = (float)s;
    }
    const float* xp = x + (size_t)plane * (128*128);
    for (int e = tid; e < MDIM*68; e += nth) {
        int i = e / 68, n = e - i*68;
        int si = (i + 124) & 127;
        int j0 = (2*n + 124) & 127;                  // always even, pair never wraps
        const float2 v = *reinterpret_cast<const float2*>(xp + si*128 + j0);
        re[i*RS + n] = v.x;
        im[i*RS + n] = v.y;
    }
    __syncthreads();
    ct68_rows<-1>(re, im, lutc, luts, tid, nth);     // rows: Z[k] at col-slot68(k)
    for (int e = tid; e < MDIM*35; e += nth) {
        int row = e / 35, k = e - row*35;
        int base = row*RS;
        int sa = slot68(k);
        float Zar = re[base+sa], Zai = im[base+sa];
        float Zbr, Zbi; int sb;
        if (k == 0) { Zbr = Zar; Zbi = Zai; sb = 68; }
        else { int kk = 68-k; sb = slot68(kk); Zbr = re[base+sb]; Zbi = im[base+sb]; }
        float wc = lutc[k], ws = luts[k];
        float Er = 0.5f*(Zar + Zbr), Ei = 0.5f*(Zai - Zbi);
        float Dr = 0.5f*(Zar - Zbr), Di = 0.5f*(Zai + Zbi);
        float Tr = wc*Dr - ws*Di, Ti = wc*Di + ws*Dr;
        re[base+sa] = Er + Ti;  im[base+sa] = Ei - Tr;
        float E2r = Er,  E2i = -Ei;
        float D2r = -Dr, D2i = Di;
        float w2c = -wc, w2s = ws;
        float T2r = w2c*D2r - w2s*D2i, T2i = w2c*D2i + w2s*D2r;
        re[base+sb] = E2r + T2i;  im[base+sb] = E2i - T2r;
    }
    __syncthreads();
    fft136_cols<-1>(re, im, lutc, luts, HC, tid, nth);
    float2* outp = Xhat + (size_t)plane * PLANE_HALF;
    for (int e = tid; e < PLANE_HALF; e += nth) {
        int g1 = e / HC, g2 = e - g1*HC;
        int cq = (g2 == 68) ? 68 : slot68(g2);
        int a = slot136(g1)*RS + cq;
        outp[e] = make_float2(re[a], im[a]);
    }
}

// ---------- Inverse: one WG per (n,c,u) (512 WGs); both v parities ----------
// v=0 results stashed in registers, then combined with v=1 into float4 stores.
// Swizzle: u = bit 3 so the u-pair (shared Xhat) lands on one XCD.
__global__ __launch_bounds__(1024, 8) void inv_kernel(const float2* __restrict__ Xhat,
                                                      const float2* __restrict__ Abuf,
                                                      float* __restrict__ out)
{
    extern __shared__ float smem[];
    float* re   = smem;
    float* im   = smem + MDIM*RS;
    float* lutc = smem + 2*MDIM*RS;
    float* luts = lutc + MDIM;
    const int tid = threadIdx.x, nth = blockDim.x;

    for (int t = tid; t < MDIM; t += nth) {
        double s, c; sincos(2.0*PI_D*(double)t/136.0, &s, &c);   // inverse direction
        lutc[t] = (float)c; luts[t] = (float)s;
    }
    const int p  = blockIdx.x;        // 0..511
    const int u  = (p >> 3) & 1;
    const int nc = ((p >> 4) << 3) | (p & 7);   // n*64 + c
    const int c  = nc & 63;
    const float2* Xp = Xhat + (size_t)nc * PLANE_HALF;
    float* op = out + (size_t)nc * (256*256);

    float st_r[8], st_i[8];

    for (int vv = 0; vv < 2; vv++) {
        const float2* Ap = Abuf + (size_t)(c*4 + u*2 + vv) * PLANE_HALF;
        for (int e = tid; e < PLANE_HALF; e += nth) {
            int g1 = e / HC, g2 = e - g1*HC;
            float2 xv = Xp[e], av = Ap[e];
            re[g1*RS + g2] = av.x*xv.x - av.y*xv.y;
            im[g1*RS + g2] = av.x*xv.y + av.y*xv.x;
        }
        __syncthreads();
        fft136_cols<1>(re, im, lutc, luts, HC, tid, nth);   // rows at slot136(y1)
        // c2r pack per row: Zf[k] = (T[k]+conj T[68-k]) + i*V^k*(T[k]-conj T[68-k]).
        for (int e = tid; e < MDIM*35; e += nth) {
            int row = e / 35, k = e - row*35;
            int base = row*RS;
            float Tar = re[base+k],    Tai = im[base+k];
            float Tbr = re[base+68-k], Tbi = im[base+68-k];
            float Sr = Tar + Tbr, Si = Tai - Tbi;
            float Dr = Tar - Tbr, Di = Tai + Tbi;
            float wc = lutc[k], ws = luts[k];               // V^k = exp(+2pi i k/136)
            float Or = wc*Dr - ws*Di, Oi = wc*Di + ws*Dr;
            re[base+k] = Sr - Oi;
            im[base+k] = Si + Or;
            if (k >= 1 && k <= 33) {
                float S2r = Tbr + Tar, S2i = Tbi - Tai;
                float D2r = Tbr - Tar, D2i = Tbi + Tai;
                float w2c = -wc, w2s = ws;                  // V^(68-k) = -conj(V^k)
                float O2r = w2c*D2r - w2s*D2i, O2i = w2c*D2i + w2s*D2r;
                re[base+68-k] = S2r - O2i;
                im[base+68-k] = S2i + O2r;
            }
        }
        __syncthreads();
        ct68_rows<1>(re, im, lutc, luts, tid, nth);         // w[m] at col-slot68(m)

        if (vv == 0) {
            // Stash v=0 results in registers (8 items/thread exactly).
#pragma unroll
            for (int it = 0; it < 8; it++) {
                int e  = tid + it*1024;
                int y1 = 4 + (e >> 6);            // [4,132)
                int m  = 2 + (e & 63);            // [2,66)
                int a  = slot136(y1)*RS + slot68(m);
                st_r[it] = re[a];
                st_i[it] = im[a];
            }
            __syncthreads();   // protect stash reads from v=1 overwrite
        } else {
            // Combine: cols 4m-8..4m-5 = (v0.re, v1.re, v0.im, v1.im).
#pragma unroll
            for (int it = 0; it < 8; it++) {
                int e  = tid + it*1024;
                int y1 = 4 + (e >> 6);
                int m  = 2 + (e & 63);
                int a  = slot136(y1)*RS + slot68(m);
                int o1 = 2*y1 + u - 8;
                float4 q;
                q.x = st_r[it];
                q.y = re[a];
                q.z = st_i[it];
                q.w = im[a];
                *reinterpret_cast<float4*>(op + o1*256 + 4*m - 8) = q;
            }
        }
    }
}

extern "C" void kernel_launch(void* const* d_in, const int* in_sizes, int n_in,
                              void* d_out, int out_size, void* d_ws, size_t ws_size,
                              hipStream_t stream)
{
    const float* x      = (const float*)d_in[0];
    const float* weight = (const float*)d_in[1];
    const float* bias   = (const float*)d_in[2];
    float* out = (float*)d_out;

    float2* Xhat = (float2*)d_ws;                       // 256 * 9384 * 8B = 19.2 MB
    float2* Abuf = Xhat + (size_t)NPLANES * PLANE_HALF; // 256 * 9384 * 8B = 19.2 MB

    const size_t lds_bytes = (size_t)LDS_FLOATS * sizeof(float);  // 77,248 B
    (void)hipFuncSetAttribute((const void*)fwdprep_kernel,
                              hipFuncAttributeMaxDynamicSharedMemorySize, (int)lds_bytes);
    (void)hipFuncSetAttribute((const void*)inv_kernel,
                              hipFuncAttributeMaxDynamicSharedMemorySize, (int)lds_bytes);

    fwdprep_kernel<<<PREP_BLOCKS + NPLANES, 1024, lds_bytes, stream>>>(x, weight, bias, Xhat, Abuf);
    inv_kernel<<<NPLANES*2, 1024, lds_bytes, stream>>>(Xhat, Abuf, out);
}

// Round 6
// 158.450 us; speedup vs baseline: 1.5139x; 1.5139x over previous
//
#include <hip/hip_runtime.h>
#include <math.h>

// Converse2D on gfx950 — spectral restructuring (R5 = R3 + fp32 prep):
//   out(2y+u, 2x+v) plane = ifft136( A_uv[g] * Xhat[g] ), per (n,c,u,v)
//   Xhat = rfft136x136(wrap_pad(x)); A_uv = per-channel multiplier (Hermitian).
// R5: revert R4's v-pair merge (it spilled to scratch: WRITE_SIZE 315 MB) and
//     prep/fwd fusion (neutral). Keep R3's inv/fwd verbatim (known 60 µs inv).
//     prep switched to fp32 (validated in R4: absmax unchanged), standalone,
//     256 thr/block, NO launch_bounds cap -> no spill risk.

#define MDIM 136
#define RS   70             // padded LDS row stride (69 stored cols + 1)
#define HC   69             // stored Hermitian half columns (0..68)
#define PLANE_HALF (MDIM*HC)   // 9384 complex per plane
#define NPLANES 256         // N*C
#define LDS_FLOATS (2*MDIM*RS + 2*MDIM)   // re+im planes + cos/sin LUT
#define PI_D 3.14159265358979323846

__device__ __forceinline__ int slot136(int k) { return 17*(k & 7) + (k >> 3); }
__device__ __forceinline__ int slot68(int k)  { return 17*(k & 3) + (k >> 2); }

// ---------- symmetric 17-point DFT, in-place on strided LDS segment ----------
template<int DIR>
__device__ __forceinline__ void dft17(float* __restrict__ re, float* __restrict__ im,
                                      int base, int stride)
{
    constexpr float C17[9] = {1.f, 0.93247223f, 0.73900892f, 0.44573836f,
                              0.09226836f, -0.27366299f, -0.60263464f,
                              -0.85021714f, -0.98297310f};
    constexpr float S17[9] = {0.f, 0.36124167f, 0.67369564f, 0.89516329f,
                              0.99573418f, 0.96182564f, 0.79801723f,
                              0.52643216f, 0.18374952f};
    constexpr float d = (DIR > 0) ? 1.f : -1.f;
    float xr[17], xi[17];
#pragma unroll
    for (int n = 0; n < 17; n++) { xr[n] = re[base + n*stride]; xi[n] = im[base + n*stride]; }
    float ar[8], ai[8], br[8], bi[8];
#pragma unroll
    for (int n = 1; n <= 8; n++) {
        ar[n-1] = xr[n] + xr[17-n];  ai[n-1] = xi[n] + xi[17-n];
        br[n-1] = xr[n] - xr[17-n];  bi[n-1] = xi[n] - xi[17-n];
    }
    float s0r = xr[0], s0i = xi[0];
#pragma unroll
    for (int n = 0; n < 8; n++) { s0r += ar[n]; s0i += ai[n]; }
    re[base] = s0r; im[base] = s0i;
#pragma unroll
    for (int k = 1; k <= 8; k++) {
        float Pr = xr[0], Pi = xi[0], Qr = 0.f, Qi = 0.f;
#pragma unroll
        for (int n = 1; n <= 8; n++) {
            int m = (k*n) % 17;
            float cc = (m <= 8) ? C17[m] : C17[17-m];
            float ss = (m <= 8) ? S17[m] : -S17[17-m];
            Pr = fmaf(ar[n-1], cc, Pr);
            Pi = fmaf(ai[n-1], cc, Pi);
            Qr = fmaf(br[n-1], ss, Qr);
            Qi = fmaf(bi[n-1], ss, Qi);
        }
        re[base + k*stride]        = Pr - d*Qi;
        im[base + k*stride]        = Pi + d*Qr;
        re[base + (17-k)*stride]   = Pr + d*Qi;
        im[base + (17-k)*stride]   = Pi - d*Qr;
    }
}

// ---------- 136-point CT (8x17) along COLUMNS ----------
template<int DIR>
__device__ void fft136_cols(float* __restrict__ re, float* __restrict__ im,
                            const float* __restrict__ lutc, const float* __restrict__ luts,
                            int ncols, int tid, int nth)
{
    constexpr float d = (DIR > 0) ? 1.0f : -1.0f;
    constexpr float C707 = 0.70710678118654752f;
    for (int e = tid; e < ncols*17; e += nth) {
        int c  = e / 17;
        int n2 = e - c*17;
        float xr[8], xi[8];
#pragma unroll
        for (int n1 = 0; n1 < 8; n1++) {
            int a = (17*n1 + n2)*RS + c;
            xr[n1] = re[a]; xi[n1] = im[a];
        }
        float e0r = xr[0]+xr[4], e0i = xi[0]+xi[4];
        float e1r = xr[0]-xr[4], e1i = xi[0]-xi[4];
        float o0r = xr[2]+xr[6], o0i = xi[2]+xi[6];
        float o1r = xr[2]-xr[6], o1i = xi[2]-xi[6];
        float E0r = e0r+o0r, E0i = e0i+o0i;
        float E2r = e0r-o0r, E2i = e0i-o0i;
        float E1r = e1r - d*o1i, E1i = e1i + d*o1r;
        float E3r = e1r + d*o1i, E3i = e1i - d*o1r;
        float f0r = xr[1]+xr[5], f0i = xi[1]+xi[5];
        float f1r = xr[1]-xr[5], f1i = xi[1]-xi[5];
        float h0r = xr[3]+xr[7], h0i = xi[3]+xi[7];
        float h1r = xr[3]-xr[7], h1i = xi[3]-xi[7];
        float O0r = f0r+h0r, O0i = f0i+h0i;
        float O2r = f0r-h0r, O2i = f0i-h0i;
        float O1r = f1r - d*h1i, O1i = f1i + d*h1r;
        float O3r = f1r + d*h1i, O3i = f1i - d*h1r;
        float t1r =  C707*(O1r - d*O1i), t1i = C707*(O1i + d*O1r);
        float t2r = -d*O2i,              t2i = d*O2r;
        float t3r = -C707*(O3r + d*O3i), t3i = C707*(d*O3r - O3i);
        float Xr[8], Xi[8];
        Xr[0]=E0r+O0r; Xi[0]=E0i+O0i;  Xr[4]=E0r-O0r; Xi[4]=E0i-O0i;
        Xr[1]=E1r+t1r; Xi[1]=E1i+t1i;  Xr[5]=E1r-t1r; Xi[5]=E1i-t1i;
        Xr[2]=E2r+t2r; Xi[2]=E2i+t2i;  Xr[6]=E2r-t2r; Xi[6]=E2i-t2i;
        Xr[3]=E3r+t3r; Xi[3]=E3i+t3i;  Xr[7]=E3r-t3r; Xi[7]=E3i-t3i;
        float wr = lutc[n2], wi = luts[n2];
        float cr = 1.f, ci = 0.f;
#pragma unroll
        for (int k1 = 0; k1 < 8; k1++) {
            int a = (17*k1 + n2)*RS + c;
            re[a] = Xr[k1]*cr - Xi[k1]*ci;
            im[a] = Xr[k1]*ci + Xi[k1]*cr;
            float ncr = cr*wr - ci*wi;
            ci = cr*wi + ci*wr; cr = ncr;
        }
    }
    __syncthreads();
    for (int e = tid; e < ncols*8; e += nth) {
        int c  = e >> 3;
        int k1 = e & 7;
        dft17<DIR>(re, im, 17*k1*RS + c, RS);
    }
    __syncthreads();
}

// ---------- 68-point CT (4x17) along ROWS ----------
template<int DIR>
__device__ void ct68_rows(float* __restrict__ re, float* __restrict__ im,
                          const float* __restrict__ lutc, const float* __restrict__ luts,
                          int tid, int nth)
{
    constexpr float d = (DIR > 0) ? 1.0f : -1.0f;
    for (int e = tid; e < MDIM*17; e += nth) {
        int row = e / 17;
        int n2  = e - row*17;
        int base = row*RS;
        float xr[4], xi[4];
#pragma unroll
        for (int n1 = 0; n1 < 4; n1++) {
            xr[n1] = re[base + 17*n1 + n2];
            xi[n1] = im[base + 17*n1 + n2];
        }
        float t0r = xr[0]+xr[2], t0i = xi[0]+xi[2];
        float t1r = xr[0]-xr[2], t1i = xi[0]-xi[2];
        float t2r = xr[1]+xr[3], t2i = xi[1]+xi[3];
        float t3r = xr[1]-xr[3], t3i = xi[1]-xi[3];
        float Xr[4], Xi[4];
        Xr[0] = t0r+t2r;      Xi[0] = t0i+t2i;
        Xr[2] = t0r-t2r;      Xi[2] = t0i-t2i;
        Xr[1] = t1r - d*t3i;  Xi[1] = t1i + d*t3r;
        Xr[3] = t1r + d*t3i;  Xi[3] = t1i - d*t3r;
        float wr = lutc[2*n2], wi = luts[2*n2];
        float cr = 1.f, ci = 0.f;
#pragma unroll
        for (int k1 = 0; k1 < 4; k1++) {
            int a = base + 17*k1 + n2;
            re[a] = Xr[k1]*cr - Xi[k1]*ci;
            im[a] = Xr[k1]*ci + Xi[k1]*cr;
            float ncr = cr*wr - ci*wi;
            ci = cr*wi + ci*wr; cr = ncr;
        }
    }
    __syncthreads();
    for (int e = tid; e < MDIM*4; e += nth) {
        int row = e >> 2;
        int k1  = e & 3;
        dft17<DIR>(re, im, row*RS + 17*k1, 1);
    }
    __syncthreads();
}

// ---------- Forward: one WG per (n,c) plane (256 WGs), r2c half-spectrum ----------
__global__ __launch_bounds__(1024, 8) void fwd_kernel(const float* __restrict__ x,
                                                      float2* __restrict__ Xhat)
{
    extern __shared__ float smem[];
    float* re   = smem;
    float* im   = smem + MDIM*RS;
    float* lutc = smem + 2*MDIM*RS;
    float* luts = lutc + MDIM;
    const int tid = threadIdx.x, nth = blockDim.x;

    for (int t = tid; t < MDIM; t += nth) {
        double s, c; sincos(-2.0*PI_D*(double)t/136.0, &s, &c);
        lutc[t] = (float)c; luts[t] = (float)s;
    }
    const float* xp = x + (size_t)blockIdx.x * (128*128);
    for (int e = tid; e < MDIM*68; e += nth) {
        int i = e / 68, n = e - i*68;
        int si = (i + 124) & 127;
        int j0 = (2*n + 124) & 127;                  // always even, pair never wraps
        const float2 v = *reinterpret_cast<const float2*>(xp + si*128 + j0);
        re[i*RS + n] = v.x;
        im[i*RS + n] = v.y;
    }
    __syncthreads();
    ct68_rows<-1>(re, im, lutc, luts, tid, nth);     // rows: Z[k] at col-slot68(k)
    // r2c unpack: X[k] = E + w136^k * O ; item k handles (k, 68-k), in-place at slots.
    for (int e = tid; e < MDIM*35; e += nth) {
        int row = e / 35, k = e - row*35;
        int base = row*RS;
        int sa = slot68(k);
        float Zar = re[base+sa], Zai = im[base+sa];
        float Zbr, Zbi; int sb;
        if (k == 0) { Zbr = Zar; Zbi = Zai; sb = 68; }
        else { int kk = 68-k; sb = slot68(kk); Zbr = re[base+sb]; Zbi = im[base+sb]; }
        float wc = lutc[k], ws = luts[k];
        float Er = 0.5f*(Zar + Zbr), Ei = 0.5f*(Zai - Zbi);
        float Dr = 0.5f*(Zar - Zbr), Di = 0.5f*(Zai + Zbi);
        float Tr = wc*Dr - ws*Di, Ti = wc*Di + ws*Dr;
        re[base+sa] = Er + Ti;  im[base+sa] = Ei - Tr;
        float E2r = Er,  E2i = -Ei;
        float D2r = -Dr, D2i = Di;
        float w2c = -wc, w2s = ws;
        float T2r = w2c*D2r - w2s*D2i, T2i = w2c*D2i + w2s*D2r;
        re[base+sb] = E2r + T2i;  im[base+sb] = E2i - T2r;
    }
    __syncthreads();
    fft136_cols<-1>(re, im, lutc, luts, HC, tid, nth);  // 69 columns
    float2* outp = Xhat + (size_t)blockIdx.x * PLANE_HALF;
    for (int e = tid; e < PLANE_HALF; e += nth) {
        int g1 = e / HC, g2 = e - g1*HC;
        int cq = (g2 == 68) ? 68 : slot68(g2);
        int a = slot136(g1)*RS + cq;
        outp[e] = make_float2(re[a], im[a]);
    }
}

// ---------- Per-channel multiplier precompute (fp32, table trig, standalone) ----------
// 8 blocks per channel, 256 threads, no launch_bounds cap (no spill risk).
// fp32 validated in R4: absmax unchanged (amplified path has bounded |FB|).
__global__ void prep_kernel(const float* __restrict__ weight,
                            const float* __restrict__ bias,
                            float2* __restrict__ Abuf)
{
    __shared__ float tabc[272], tabs[272];   // exp(-2*pi*i*t/272)
    __shared__ float wsh[25];
    const int c     = blockIdx.x >> 3;
    const int chunk = blockIdx.x & 7;
    for (int t = threadIdx.x; t < 272; t += blockDim.x) {
        float s, co; sincosf((float)(-2.0*PI_D/272.0)*(float)t, &s, &co);
        tabc[t] = co; tabs[t] = s;
    }
    if (threadIdx.x < 25) wsh[threadIdx.x] = weight[c*25 + threadIdx.x];
    __syncthreads();
    const float r = 1.f/(1.f + expf(9.f - bias[c])) + 1e-5f;
    const float scale = 1.f/73984.f;         // 1/272^2 ifft normalization

    const int e_lo = chunk * 1173;           // 8*1173 == PLANE_HALF
    const int e_hi = e_lo + 1173;
    for (int e = e_lo + (int)threadIdx.x; e < e_hi; e += blockDim.x) {
        int g1 = e / HC, g2 = e - g1*HC;
        float c1 = tabc[g1], s1 = tabs[g1];
        float c2 = tabc[g2], s2 = tabs[g2];
        float e1r[5], e1i[5], e2r[5], e2i[5];
        e1r[2]=1.f; e1i[2]=0.f; e1r[3]=c1; e1i[3]=s1;
        e1r[4]=c1*c1-s1*s1; e1i[4]=2.f*c1*s1;
        e1r[1]=c1; e1i[1]=-s1; e1r[0]=e1r[4]; e1i[0]=-e1i[4];
        e2r[2]=1.f; e2i[2]=0.f; e2r[3]=c2; e2i[3]=s2;
        e2r[4]=c2*c2-s2*s2; e2i[4]=2.f*c2*s2;
        e2r[1]=c2; e2i[1]=-s2; e2r[0]=e2r[4]; e2i[0]=-e2i[4];

        float Fr[2][2] = {{0,0},{0,0}}, Fi[2][2] = {{0,0},{0,0}};
#pragma unroll
        for (int a = 0; a < 5; a++) {
            float r0r=0,r0i=0,r1r=0,r1i=0;
#pragma unroll
            for (int b = 0; b < 5; b++) {
                float wv = wsh[a*5+b];
                float pr = wv*e2r[b], pi = wv*e2i[b];
                r0r += pr; r0i += pi;
                if (b & 1) { r1r -= pr; r1i -= pi; } else { r1r += pr; r1i += pi; }
            }
            float Er = e1r[a], Ei = e1i[a];
            float t0r = Er*r0r - Ei*r0i, t0i = Er*r0i + Ei*r0r;
            float t1r = Er*r1r - Ei*r1i, t1i = Er*r1i + Ei*r1r;
            Fr[0][0] += t0r; Fi[0][0] += t0i; Fr[0][1] += t1r; Fi[0][1] += t1i;
            if (a & 1) { Fr[1][0] -= t0r; Fi[1][0] -= t0i; Fr[1][1] -= t1r; Fi[1][1] -= t1i; }
            else       { Fr[1][0] += t0r; Fi[1][0] += t0i; Fr[1][1] += t1r; Fi[1][1] += t1i; }
        }
        float ur[2] = {1.f+c1, 1.f-c1}, ui[2] = {s1, -s1};
        float vr[2] = {1.f+c2, 1.f-c2}, vi[2] = {s2, -s2};
        float Br[2][2], Bi[2][2];
        float invW = 0.f, Qr = 0.f, Qi = 0.f;
#pragma unroll
        for (int a1 = 0; a1 < 2; a1++)
#pragma unroll
            for (int b1 = 0; b1 < 2; b1++) {
                Br[a1][b1] = ur[a1]*vr[b1] - ui[a1]*vi[b1];
                Bi[a1][b1] = ur[a1]*vi[b1] + ui[a1]*vr[b1];
                invW += Fr[a1][b1]*Fr[a1][b1] + Fi[a1][b1]*Fi[a1][b1];
                Qr += Fr[a1][b1]*Br[a1][b1] - Fi[a1][b1]*Bi[a1][b1];
                Qi += Fr[a1][b1]*Bi[a1][b1] + Fi[a1][b1]*Br[a1][b1];
            }
        invW *= 0.25f; Qr *= 0.25f; Qi *= 0.25f;
        float den = 1.f/(invW + r);
        float Sr = (1.f - Qr)*den, Si = -Qi*den;
        float Mr[2][2], Mi[2][2];
#pragma unroll
        for (int a1 = 0; a1 < 2; a1++)
#pragma unroll
            for (int b1 = 0; b1 < 2; b1++) {
                Mr[a1][b1] = Br[a1][b1] + Fr[a1][b1]*Sr + Fi[a1][b1]*Si;
                Mi[a1][b1] = Bi[a1][b1] + Fr[a1][b1]*Si - Fi[a1][b1]*Sr;
            }
#pragma unroll
        for (int uu = 0; uu < 2; uu++)
#pragma unroll
            for (int vv = 0; vv < 2; vv++) {
                float sr=0.f, si=0.f;
#pragma unroll
                for (int a1 = 0; a1 < 2; a1++)
#pragma unroll
                    for (int b1 = 0; b1 < 2; b1++) {
                        if ((a1*uu + b1*vv) & 1) { sr -= Mr[a1][b1]; si -= Mi[a1][b1]; }
                        else                     { sr += Mr[a1][b1]; si += Mi[a1][b1]; }
                    }
                int t = g1*uu + g2*vv;              // <= 203 < 272
                float pc = tabc[t], ps = -tabs[t];  // exp(+i*pi*t/136)
                float2 outv;
                outv.x = (pc*sr - ps*si)*scale;
                outv.y = (pc*si + ps*sr)*scale;
                Abuf[((size_t)(c*4 + uu*2 + vv))*PLANE_HALF + e] = outv;
            }
    }
}

// ---------- Inverse: one WG per (n,c,u,v) (1024 WGs), Hermitian half-spectrum ----------
// blockIdx swizzle: v = bit 3 so the v-pair (same nc,u) is 8 apart -> same XCD
// (blockIdx%8 round-robin) -> their interleaved partial-line writes merge in L2.
__global__ __launch_bounds__(1024, 8) void inv_kernel(const float2* __restrict__ Xhat,
                                                      const float2* __restrict__ Abuf,
                                                      float* __restrict__ out)
{
    extern __shared__ float smem[];
    float* re   = smem;
    float* im   = smem + MDIM*RS;
    float* lutc = smem + 2*MDIM*RS;
    float* luts = lutc + MDIM;
    const int tid = threadIdx.x, nth = blockDim.x;

    for (int t = tid; t < MDIM; t += nth) {
        double s, c; sincos(2.0*PI_D*(double)t/136.0, &s, &c);   // inverse direction
        lutc[t] = (float)c; luts[t] = (float)s;
    }
    const int p  = blockIdx.x;        // 0..1023
    const int u  = p & 1;
    const int v  = (p >> 3) & 1;
    const int nc = ((p >> 4) << 2) | ((p >> 1) & 3);   // n*64 + c
    const int c  = nc & 63;
    const float2* Xp = Xhat + (size_t)nc * PLANE_HALF;
    const float2* Ap = Abuf + (size_t)(c*4 + u*2 + v) * PLANE_HALF;

    // Load S = A_uv * Xhat, natural [g1][g2], g2 = 0..68. (S is Hermitian.)
    for (int e = tid; e < PLANE_HALF; e += nth) {
        int g1 = e / HC, g2 = e - g1*HC;
        float2 xv = Xp[e], av = Ap[e];
        re[g1*RS + g2] = av.x*xv.x - av.y*xv.y;
        im[g1*RS + g2] = av.x*xv.y + av.y*xv.x;
    }
    __syncthreads();
    fft136_cols<1>(re, im, lutc, luts, HC, tid, nth);   // rows become slot136(y1)
    // c2r pack per row: Zf[k] = (T[k]+conj T[68-k]) + i*V^k*(T[k]-conj T[68-k]).
    for (int e = tid; e < MDIM*35; e += nth) {
        int row = e / 35, k = e - row*35;
        int base = row*RS;
        float Tar = re[base+k],    Tai = im[base+k];
        float Tbr = re[base+68-k], Tbi = im[base+68-k];
        float Sr = Tar + Tbr, Si = Tai - Tbi;
        float Dr = Tar - Tbr, Di = Tai + Tbi;
        float wc = lutc[k], ws = luts[k];               // V^k = exp(+2pi i k/136)
        float Or = wc*Dr - ws*Di, Oi = wc*Di + ws*Dr;
        re[base+k] = Sr - Oi;                           // Zf[k] = S + i*O
        im[base+k] = Si + Or;
        if (k >= 1 && k <= 33) {                        // Zf[68-k]
            float S2r = Tbr + Tar, S2i = Tbi - Tai;
            float D2r = Tbr - Tar, D2i = Tbi + Tai;
            float w2c = -wc, w2s = ws;                  // V^(68-k) = -conj(V^k)
            float O2r = w2c*D2r - w2s*D2i, O2i = w2c*D2i + w2s*D2r;
            re[base+68-k] = S2r - O2i;
            im[base+68-k] = S2i + O2r;
        }
    }
    __syncthreads();
    ct68_rows<1>(re, im, lutc, luts, tid, nth);         // w[m] at col-slot68(m)
    // Store: row y1 at physical slot136(y1); re -> col 4m+v-8, im -> col 4m+v-6.
    float* op = out + (size_t)nc * (256*256);
    for (int e = tid; e < 128*64; e += nth) {
        int y1 = 4 + (e >> 6);            // [4,132)
        int m  = 2 + (e & 63);            // [2,66)
        int a  = slot136(y1)*RS + slot68(m);
        int o1 = 2*y1 + u - 8;
        float wr = re[a], wi = im[a];
        op[o1*256 + 4*m + v - 8] = wr;    // y2' = 2m   (even within parity grid)
        op[o1*256 + 4*m + v - 6] = wi;    // y2' = 2m+1
    }
}

extern "C" void kernel_launch(void* const* d_in, const int* in_sizes, int n_in,
                              void* d_out, int out_size, void* d_ws, size_t ws_size,
                              hipStream_t stream)
{
    const float* x      = (const float*)d_in[0];
    const float* weight = (const float*)d_in[1];
    const float* bias   = (const float*)d_in[2];
    float* out = (float*)d_out;

    float2* Xhat = (float2*)d_ws;                       // 256 * 9384 * 8B = 19.2 MB
    float2* Abuf = Xhat + (size_t)NPLANES * PLANE_HALF; // 256 * 9384 * 8B = 19.2 MB

    const size_t lds_bytes = (size_t)LDS_FLOATS * sizeof(float);  // 77,248 B
    (void)hipFuncSetAttribute((const void*)fwd_kernel,
                              hipFuncAttributeMaxDynamicSharedMemorySize, (int)lds_bytes);
    (void)hipFuncSetAttribute((const void*)inv_kernel,
                              hipFuncAttributeMaxDynamicSharedMemorySize, (int)lds_bytes);

    prep_kernel<<<512, 256, 0, stream>>>(weight, bias, Abuf);
    fwd_kernel<<<NPLANES, 1024, lds_bytes, stream>>>(x, Xhat);
    inv_kernel<<<NPLANES*4, 1024, lds_bytes, stream>>>(Xhat, Abuf, out);
}